// Round 1
// baseline (177.430 us; speedup 1.0000x reference)
//
#include <hip/hip_runtime.h>
#include <math.h>

#define NB   128
#define NG   52
#define NGG  (NG*NG)        // 2704
#define NA   3
#define NCLS 15
#define NCH  20
#define NQ   (NA*NGG)       // 8112
#define TOTAL (NB*NQ)       // 1038336
#define BLK  256
#define NBLK (TOTAL/BLK)    // 4056 (exact)

#define REC_STRIDE 16
#define ACC_OFF (NB*REC_STRIDE)

// ---------------- kernel 1: per-batch target prep (tiny) ----------------
__global__ void prep_kernel(const float* __restrict__ labels, float* __restrict__ ws) {
    int b = threadIdx.x;
    if (b == 0) ws[ACC_OFF] = 0.0f;   // zero the noobj-sum accumulator
    if (b < NB) {
        float gx = labels[b*5+0] * (float)NG;
        float gy = labels[b*5+1] * (float)NG;
        float gw = labels[b*5+2] * (float)NG;
        float gh = labels[b*5+3] * (float)NG;
        int gcls = (int)labels[b*5+4];
        int gi = (int)gx, gj = (int)gy;
        const float aw[3] = {12.0f, 9.875f, 10.125f};
        const float ah[3] = {28.75f, 23.25f, 16.625f};
        float iou[3];
        #pragma unroll
        for (int a = 0; a < 3; a++) {
            float inter = fminf(aw[a], gw) * fminf(ah[a], gh);
            iou[a] = inter / (aw[a]*ah[a] + 1e-16f + gw*gh - inter);
        }
        int best = 0; float bv = iou[0];
        if (iou[1] > bv) { best = 1; bv = iou[1]; }
        if (iou[2] > bv) { best = 2; bv = iou[2]; }
        float* r = ws + b*REC_STRIDE;
        r[0]  = __int_as_float(best);
        r[1]  = __int_as_float(gi);
        r[2]  = __int_as_float(gj);
        r[3]  = __int_as_float(gcls);
        r[4]  = gx - (float)gi;                       // tx target
        r[5]  = gy - (float)gj;                       // ty target
        r[6]  = logf(gw / aw[best] + 1e-16f);         // tw target
        r[7]  = logf(gh / ah[best] + 1e-16f);         // th target
        r[8]  = (iou[0] > 0.5f) ? 1.0f : 0.0f;        // ignore flags
        r[9]  = (iou[1] > 0.5f) ? 1.0f : 0.0f;
        r[10] = (iou[2] > 0.5f) ? 1.0f : 0.0f;
    }
}

// ---------------- kernel 2: main transform + noobj BCE sum ----------------
__global__ __launch_bounds__(BLK) void main_kernel(const float* __restrict__ x,
                                                   float* __restrict__ out,   // d_out (loss at [0], out at [1..])
                                                   float* __restrict__ acc) {
    int tid = threadIdx.x;
    int idx = blockIdx.x * BLK + tid;          // cell index, < TOTAL
    int b  = idx / NQ;
    int r  = idx - b * NQ;
    int a  = r / NGG;
    int ji = r - a * NGG;

    const float* xp = x + ((size_t)(b*60 + a*20)) * NGG + ji;
    float z[NCH];
    #pragma unroll
    for (int c = 0; c < NCH; c++) z[c] = xp[(size_t)c * NGG];

    float px   = 1.0f / (1.0f + expf(-z[0]));
    float py   = 1.0f / (1.0f + expf(-z[1]));
    float conf = 1.0f / (1.0f + expf(-z[4]));

    // softmax over channels 5..19 (max-subtracted, as jax.nn.softmax)
    float m = z[5];
    #pragma unroll
    for (int c = 6; c < NCH; c++) m = fmaxf(m, z[c]);
    float e[NCLS]; float s = 0.0f;
    #pragma unroll
    for (int c = 0; c < NCLS; c++) { e[c] = expf(z[5+c] - m); s += e[c]; }
    float inv = 1.0f / s;

    float v[NCH];
    v[0] = px * 8.0f; v[1] = py * 8.0f; v[2] = z[2] * 8.0f; v[3] = z[3] * 8.0f;
    v[4] = conf;
    #pragma unroll
    for (int c = 0; c < NCLS; c++) v[5+c] = e[c] * inv;

    // noobj BCE term assuming noobj==1 everywhere (corrected in kernel 3)
    float term = -fmaxf(logf(1.0f - conf), -100.0f);

    // stage outputs in LDS with stride-21 padding (bank-conflict-free)
    __shared__ float sm[BLK * 21];
    #pragma unroll
    for (int c = 0; c < NCH; c++) sm[tid*21 + c] = v[c];

    // wave-level reduction of noobj sum
    float rs = term;
    #pragma unroll
    for (int off = 32; off > 0; off >>= 1) rs += __shfl_down(rs, off, 64);
    __shared__ float wsum[BLK/64];
    if ((tid & 63) == 0) wsum[tid >> 6] = rs;

    __syncthreads();

    // coalesced dword stores: flat position p = k*BLK + tid within block's 5120 floats
    size_t ob = 1 + (size_t)blockIdx.x * (BLK * NCH);
    int cell = tid / NCH, cc = tid - (tid / NCH) * NCH;
    #pragma unroll
    for (int k = 0; k < NCH; k++) {
        out[ob + (size_t)k*BLK + tid] = sm[cell*21 + cc];
        cc += 16; cell += 12;                 // advance p by 256 = 12*20 + 16
        if (cc >= NCH) { cc -= NCH; cell++; }
    }

    if (tid == 0) atomicAdd(acc, wsum[0] + wsum[1] + wsum[2] + wsum[3]);
}

// ---------------- kernel 3: corrections + final loss ----------------
__global__ void finish_kernel(const float* __restrict__ ws, float* __restrict__ out) {
    int b = threadIdx.x;   // 128 threads
    float partial = 0.0f;
    {
        const float* r = ws + b*REC_STRIDE;
        int best = __float_as_int(r[0]);
        int gi   = __float_as_int(r[1]);
        int gj   = __float_as_int(r[2]);
        int gcls = __float_as_int(r[3]);
        float txv = r[4], tyv = r[5], twv = r[6], thv = r[7];
        float ign[3] = { r[8], r[9], r[10] };
        float corr = 0.0f;
        #pragma unroll
        for (int a = 0; a < 3; a++) {
            int q = a*NGG + gj*NG + gi;
            const float* ob = out + 1 + ((size_t)b*NQ + q) * NCH;
            float conf = ob[4];
            bool isbest = (a == best);
            if (isbest || ign[a] > 0.5f) {
                // this position has noobj==0: remove its contribution from the big sum
                corr += -fmaxf(logf(1.0f - conf), -100.0f);
            }
            if (isbest) {
                // obj conf BCE (t=1)
                partial += -fmaxf(logf(conf), -100.0f);
                // L1 coordinate losses
                float px = ob[0]*0.125f, py = ob[1]*0.125f;
                float pw = ob[2]*0.125f, ph = ob[3]*0.125f;
                partial += fabsf(px - txv) + fabsf(py - tyv)
                         + fabsf(pw - twv) + fabsf(ph - thv);
                // class BCE at the obj cell
                for (int c = 0; c < NCLS; c++) {
                    float p = ob[5 + c];
                    if (c == gcls) partial += -fmaxf(logf(p),        -100.0f);
                    else           partial += -fmaxf(logf(1.0f - p), -100.0f);
                }
            }
        }
        partial -= 100.0f * corr;
    }
    __shared__ float red[128];
    red[b] = partial;
    __syncthreads();
    for (int s2 = 64; s2 > 0; s2 >>= 1) {
        if (b < s2) red[b] += red[b + s2];
        __syncthreads();
    }
    if (b == 0) out[0] = red[0] + 100.0f * ws[ACC_OFF];
}

extern "C" void kernel_launch(void* const* d_in, const int* in_sizes, int n_in,
                              void* d_out, int out_size, void* d_ws, size_t ws_size,
                              hipStream_t stream) {
    const float* x      = (const float*)d_in[0];
    const float* labels = (const float*)d_in[1];
    float* out = (float*)d_out;
    float* ws  = (float*)d_ws;

    hipLaunchKernelGGL(prep_kernel,   dim3(1),    dim3(128), 0, stream, labels, ws);
    hipLaunchKernelGGL(main_kernel,   dim3(NBLK), dim3(BLK), 0, stream, x, out, ws + ACC_OFF);
    hipLaunchKernelGGL(finish_kernel, dim3(1),    dim3(128), 0, stream, ws, out);
}

// Round 2
// 157.316 us; speedup vs baseline: 1.1279x; 1.1279x over previous
//
#include <hip/hip_runtime.h>
#include <math.h>

#define NB    128
#define NG    52
#define NGG   2704          // NG*NG
#define NA    3
#define NCLS  15
#define NCH   20
#define NQ    8112          // NA*NGG
#define TOTAL 1038336       // NB*NQ
#define BLK   256
#define CPT   2             // cells per thread
#define CPB   (BLK*CPT)     // 512 cells per block
#define NBLK  (TOTAL/CPB)   // 2028 (exact)
#define FPB   (CPB*NCH)     // 10240 output floats per block
#define NQUAD ((FPB-4)/4)   // 2559 aligned float4 stores per block

// ---------------- main kernel: transform + per-block noobj BCE partial ----
__global__ __launch_bounds__(BLK) void main_kernel(const float* __restrict__ x,
                                                   float* __restrict__ out,
                                                   float* __restrict__ partials) {
    __shared__ __align__(16) float sm[FPB];   // block's 10240 out floats, shifted by -3
    __shared__ float wred[BLK/64];

    int t = threadIdx.x;
    int g = blockIdx.x * BLK + t;     // pair-of-cells index
    int cell0 = g * CPT;
    int b  = cell0 / NQ;
    int r  = cell0 - b * NQ;
    int a  = r / NGG;
    int ji = r - a * NGG;             // even; both cells in same (b,a) plane

    const float2* __restrict__ xp =
        (const float2*)(x + ((size_t)(b*60 + a*20)) * NGG) + (ji >> 1);

    float za[NCH], zb[NCH];
    #pragma unroll
    for (int c = 0; c < NCH; c++) {
        float2 zz = xp[c * (NGG/2)];
        za[c] = zz.x; zb[c] = zz.y;
    }

    float tsum = 0.0f;
    #pragma unroll
    for (int i = 0; i < CPT; i++) {
        const float* z = (i == 0) ? za : zb;
        float v[NCH];
        float conf = 1.0f / (1.0f + expf(-z[4]));
        v[0] = 8.0f / (1.0f + expf(-z[0]));
        v[1] = 8.0f / (1.0f + expf(-z[1]));
        v[2] = 8.0f * z[2];
        v[3] = 8.0f * z[3];
        v[4] = conf;
        float m = z[5];
        #pragma unroll
        for (int c = 6; c < NCH; c++) m = fmaxf(m, z[c]);
        float s = 0.0f;
        #pragma unroll
        for (int c = 0; c < NCLS; c++) { v[5+c] = expf(z[5+c] - m); s += v[5+c]; }
        float inv = 1.0f / s;
        #pragma unroll
        for (int c = 0; c < NCLS; c++) v[5+c] *= inv;

        tsum += -fmaxf(logf(1.0f - conf), -100.0f);   // noobj term (corrected later)

        int cl = (t * CPT + i);                        // cell index within block
        int base = cl * NCH - 3;                       // shifted LDS layout
        #pragma unroll
        for (int c = 0; c < NCH; c++) {
            int L = base + c;
            if (L < 0) L += FPB;                       // only cl==0, c<3
            sm[L] = v[c];
        }
    }

    // wave reduce noobj partial
    #pragma unroll
    for (int off = 32; off > 0; off >>= 1) tsum += __shfl_down(tsum, off, 64);
    if ((t & 63) == 0) wred[t >> 6] = tsum;

    __syncthreads();

    // coalesced float4 stores of the block's contiguous out region
    size_t gbase = (size_t)blockIdx.x * FPB;           // out index base (out[0] is loss)
    float4* __restrict__ op = (float4*)(out + gbase + 4);
    const float4* __restrict__ sp = (const float4*)sm;
    #pragma unroll
    for (int k = 0; k < 10; k++) {
        int q = k * BLK + t;
        if (q < NQUAD) op[q] = sp[q];
    }
    if (t == 0) {
        out[gbase + 1]    = sm[FPB - 3];   // j_local 0
        out[gbase + 2]    = sm[FPB - 2];   // j_local 1
        out[gbase + 3]    = sm[FPB - 1];   // j_local 2
        out[gbase + FPB]  = sm[FPB - 4];   // j_local FPB-1 (trailing scalar)
        partials[blockIdx.x] = wred[0] + wred[1] + wred[2] + wred[3];
    }
}

// ---------------- finish: partial sum + per-batch corrections + loss ------
__global__ void finish_kernel(const float* __restrict__ labels,
                              const float* __restrict__ partials,
                              float* __restrict__ out) {
    int t = threadIdx.x;   // 256 threads
    float s = 0.0f;
    for (int q = t; q < NBLK; q += 256) s += partials[q];

    float corr_part = 0.0f;
    if (t < NB) {
        int b = t;
        float gx = labels[b*5+0] * (float)NG;
        float gy = labels[b*5+1] * (float)NG;
        float gw = labels[b*5+2] * (float)NG;
        float gh = labels[b*5+3] * (float)NG;
        int gcls = (int)labels[b*5+4];
        int gi = (int)gx, gj = (int)gy;
        const float aw[3] = {12.0f, 9.875f, 10.125f};
        const float ah[3] = {28.75f, 23.25f, 16.625f};
        float iou[3];
        #pragma unroll
        for (int a = 0; a < 3; a++) {
            float inter = fminf(aw[a], gw) * fminf(ah[a], gh);
            iou[a] = inter / (aw[a]*ah[a] + 1e-16f + gw*gh - inter);
        }
        int best = 0; float bv = iou[0];
        if (iou[1] > bv) { best = 1; bv = iou[1]; }
        if (iou[2] > bv) { best = 2; bv = iou[2]; }
        float txv = gx - (float)gi;
        float tyv = gy - (float)gj;
        float twv = logf(gw / aw[best] + 1e-16f);
        float thv = logf(gh / ah[best] + 1e-16f);

        float corr = 0.0f;
        #pragma unroll
        for (int a = 0; a < 3; a++) {
            int q = a*NGG + gj*NG + gi;
            const float* ob = out + 1 + ((size_t)b*NQ + q) * NCH;
            float conf = ob[4];
            bool isbest = (a == best);
            if (isbest || iou[a] > 0.5f) {
                corr += -fmaxf(logf(1.0f - conf), -100.0f);   // noobj==0 here: remove
            }
            if (isbest) {
                corr_part += -fmaxf(logf(conf), -100.0f);     // obj conf BCE (t=1)
                float px = ob[0]*0.125f, py = ob[1]*0.125f;
                float pw = ob[2]*0.125f, ph = ob[3]*0.125f;
                corr_part += fabsf(px - txv) + fabsf(py - tyv)
                           + fabsf(pw - twv) + fabsf(ph - thv);
                for (int c = 0; c < NCLS; c++) {
                    float p = ob[5 + c];
                    if (c == gcls) corr_part += -fmaxf(logf(p),        -100.0f);
                    else           corr_part += -fmaxf(logf(1.0f - p), -100.0f);
                }
            }
        }
        corr_part -= 100.0f * corr;
    }

    __shared__ float red[256];
    red[t] = 100.0f * s + corr_part;
    __syncthreads();
    for (int s2 = 128; s2 > 0; s2 >>= 1) {
        if (t < s2) red[t] += red[t + s2];
        __syncthreads();
    }
    if (t == 0) out[0] = red[0];
}

extern "C" void kernel_launch(void* const* d_in, const int* in_sizes, int n_in,
                              void* d_out, int out_size, void* d_ws, size_t ws_size,
                              hipStream_t stream) {
    const float* x      = (const float*)d_in[0];
    const float* labels = (const float*)d_in[1];
    float* out = (float*)d_out;
    float* ws  = (float*)d_ws;

    hipLaunchKernelGGL(main_kernel,   dim3(NBLK), dim3(BLK), 0, stream, x, out, ws);
    hipLaunchKernelGGL(finish_kernel, dim3(1),    dim3(256), 0, stream, labels, ws, out);
}